// Round 1
// baseline (476.628 us; speedup 1.0000x reference)
//
#include <hip/hip_runtime.h>
#include <hip/hip_bf16.h>
#include <math.h>

#define B_  16
#define C_  64
#define H_  192
#define W_  192
#define R_  64
#define HW_ (H_*W_)            // 36864

// ---------------- ws layout (floats) ----------------
// cp   : [B][C]        off 0      size 1024
// hp   : [B][H]        off 1024   size 3072   (atomic accum, needs zero)
// wp   : [B][W]        off 4096   size 3072   (atomic accum, needs zero)
// Mw   : [B][R][C]     off 7168   size 65536  (= p[r]*sigmoid(Wc.cp+bc))
// Hws  : [B][H][R]     off 72704  size 196608
// Wws  : [B][W][R]     off 269312 size 196608
#define OFF_CP  0
#define OFF_HP  1024
#define OFF_WP  4096
#define OFF_MW  7168
#define OFF_HWS 72704
#define OFF_WWS 269312

__global__ __launch_bounds__(256) void zero_kernel(float* p, int n) {
    int i = blockIdx.x * 256 + threadIdx.x;
    if (i < n) p[i] = 0.f;
}

// One block per (b,c): reduces a 192x192 slice.
// threads = 192, thread t owns column w=t.
__global__ __launch_bounds__(192) void pool_kernel(const float* __restrict__ X,
                                                   float* __restrict__ cp,
                                                   float* __restrict__ hp,
                                                   float* __restrict__ wp) {
    int b = blockIdx.x >> 6;
    int c = blockIdx.x & 63;
    int t = threadIdx.x;           // w index
    int wave = t >> 6, lane = t & 63;
    const float* base = X + (size_t)(b * C_ + c) * HW_;

    __shared__ float rowpart[H_ * 3];
    __shared__ float cpart[3];

    float col = 0.f;
    for (int h = 0; h < H_; ++h) {
        float x = base[h * W_ + t];
        col += x;
        float s = x;
        s += __shfl_down(s, 32);
        s += __shfl_down(s, 16);
        s += __shfl_down(s, 8);
        s += __shfl_down(s, 4);
        s += __shfl_down(s, 2);
        s += __shfl_down(s, 1);
        if (lane == 0) rowpart[h * 3 + wave] = s;
    }
    // cp reduction over the block
    float s = col;
    s += __shfl_down(s, 32);
    s += __shfl_down(s, 16);
    s += __shfl_down(s, 8);
    s += __shfl_down(s, 4);
    s += __shfl_down(s, 2);
    s += __shfl_down(s, 1);
    if (lane == 0) cpart[wave] = s;
    __syncthreads();

    const float inv_cw = 1.0f / 12288.0f;   // 1/(C*W) == 1/(C*H)
    float hs = rowpart[t * 3 + 0] + rowpart[t * 3 + 1] + rowpart[t * 3 + 2];
    atomicAdd(&hp[b * H_ + t], hs * inv_cw);
    atomicAdd(&wp[b * W_ + t], col * inv_cw);
    if (t == 0) cp[b * C_ + c] = (cpart[0] + cpart[1] + cpart[2]) * (1.0f / (float)HW_);
}

// Generic: out[...] = (p?p[r]:1) * sigmoid( dot(Wsrc[row,:K], pool[b,:K]) + bias[row] )
// row = blockIdx.x*16 + (tid>>4), b = tid&15.  rows total = R_*D.
__global__ __launch_bounds__(256) void affine_sig_kernel(const float* __restrict__ Wsrc,
                                                         const float* __restrict__ bias,
                                                         const float* __restrict__ pool,
                                                         const float* __restrict__ p,
                                                         float* __restrict__ out,
                                                         int D, int K,
                                                         int s_b, int s_d, int s_r) {
    __shared__ float pl[16 * 193];   // [16][K+1] padded, K<=192
    int tid = threadIdx.x;
    for (int i = tid; i < 16 * K; i += 256) {
        int bb = i / K, kk = i - bb * K;
        pl[bb * (K + 1) + kk] = pool[i];
    }
    __syncthreads();

    int b  = tid & 15;
    int rl = tid >> 4;
    int row = blockIdx.x * 16 + rl;
    int r = row / D, d = row - r * D;

    const float4* w4 = (const float4*)(Wsrc + (size_t)row * K);
    const float*  pb = &pl[b * (K + 1)];
    float acc = 0.f;
    for (int k4 = 0; k4 < (K >> 2); ++k4) {
        float4 wv = w4[k4];
        int k = k4 << 2;
        acc += wv.x * pb[k] + wv.y * pb[k + 1] + wv.z * pb[k + 2] + wv.w * pb[k + 3];
    }
    acc += bias[row];
    float sgm = 1.0f / (1.0f + expf(-acc));
    if (p) sgm *= p[r];
    out[(size_t)b * s_b + (size_t)d * s_d + (size_t)r * s_r] = sgm;
}

// One block per (b, h, 64-wide w strip). 256 threads.
// Computes out[b, 0:64, h, w0:w0+64] = X * (M^T g), M=[r][c], g[r][j]=Hv[r]*Wt[r][j].
__global__ __launch_bounds__(256) void main_kernel(const float* __restrict__ X,
                                                   const float* __restrict__ Mw,
                                                   const float* __restrict__ Hws,
                                                   const float* __restrict__ Wws,
                                                   float* __restrict__ out) {
    __shared__ float Ml[R_ * C_];   // [r][c]
    __shared__ float Gl[R_ * 64];   // [r][j]
    __shared__ float Hv[R_];

    int blk = blockIdx.x;
    int b = blk / 576;
    int strip = blk - b * 576;
    int h = strip / 3;
    int w0 = (strip - h * 3) * 64;
    int tid = threadIdx.x;

    // stage M (p[r]*Cw), 4096 floats
    {
        const float4* src = (const float4*)(Mw + (size_t)b * (R_ * C_));
        float4* dst = (float4*)Ml;
        #pragma unroll
        for (int i = 0; i < 4; ++i) dst[tid + i * 256] = src[tid + i * 256];
    }
    if (tid < 64) Hv[tid] = Hws[((size_t)b * H_ + h) * R_ + tid];
    // stage Wt transposed into Gl[r][j]
    {
        int j = tid >> 2, q = tid & 3;
        const float4* src = (const float4*)(Wws + ((size_t)b * W_ + w0 + j) * R_ + q * 16);
        float4 v0 = src[0], v1 = src[1], v2 = src[2], v3 = src[3];
        int rb = q * 16;
        Gl[(rb + 0) * 64 + j] = v0.x;  Gl[(rb + 1) * 64 + j] = v0.y;
        Gl[(rb + 2) * 64 + j] = v0.z;  Gl[(rb + 3) * 64 + j] = v0.w;
        Gl[(rb + 4) * 64 + j] = v1.x;  Gl[(rb + 5) * 64 + j] = v1.y;
        Gl[(rb + 6) * 64 + j] = v1.z;  Gl[(rb + 7) * 64 + j] = v1.w;
        Gl[(rb + 8) * 64 + j] = v2.x;  Gl[(rb + 9) * 64 + j] = v2.y;
        Gl[(rb + 10) * 64 + j] = v2.z; Gl[(rb + 11) * 64 + j] = v2.w;
        Gl[(rb + 12) * 64 + j] = v3.x; Gl[(rb + 13) * 64 + j] = v3.y;
        Gl[(rb + 14) * 64 + j] = v3.z; Gl[(rb + 15) * 64 + j] = v3.w;
    }
    __syncthreads();
    // fold Hv into G (g[r][j] = Hv[r] * Wt[r][j])
    #pragma unroll
    for (int i = 0; i < 16; ++i) {
        int idx = tid + i * 256;
        Gl[idx] *= Hv[idx >> 6];
    }
    __syncthreads();

    int j  = tid & 63;
    int cg = tid >> 6;        // 0..3
    int c0 = cg * 16;

    float acc[16];
    #pragma unroll
    for (int k = 0; k < 16; ++k) acc[k] = 0.f;

    #pragma unroll 4
    for (int r = 0; r < R_; ++r) {
        float g = Gl[r * 64 + j];
        const float4* mr = (const float4*)(Ml + r * C_ + c0);
        float4 m0 = mr[0], m1 = mr[1], m2 = mr[2], m3 = mr[3];
        acc[0]  += g * m0.x;  acc[1]  += g * m0.y;
        acc[2]  += g * m0.z;  acc[3]  += g * m0.w;
        acc[4]  += g * m1.x;  acc[5]  += g * m1.y;
        acc[6]  += g * m1.z;  acc[7]  += g * m1.w;
        acc[8]  += g * m2.x;  acc[9]  += g * m2.y;
        acc[10] += g * m2.z;  acc[11] += g * m2.w;
        acc[12] += g * m3.x;  acc[13] += g * m3.y;
        acc[14] += g * m3.z;  acc[15] += g * m3.w;
    }

    size_t pix = (size_t)h * W_ + w0 + j;
    #pragma unroll
    for (int k = 0; k < 16; ++k) {
        size_t idx = (size_t)(b * C_ + c0 + k) * HW_ + pix;
        out[idx] = acc[k] * X[idx];
    }
}

extern "C" void kernel_launch(void* const* d_in, const int* in_sizes, int n_in,
                              void* d_out, int out_size, void* d_ws, size_t ws_size,
                              hipStream_t stream) {
    const float* X  = (const float*)d_in[0];
    const float* p  = (const float*)d_in[1];
    const float* Wc = (const float*)d_in[2];
    const float* bc = (const float*)d_in[3];
    const float* Wh = (const float*)d_in[4];
    const float* bh = (const float*)d_in[5];
    const float* Ww = (const float*)d_in[6];
    const float* bw = (const float*)d_in[7];
    float* out = (float*)d_out;
    float* ws  = (float*)d_ws;

    float* cp  = ws + OFF_CP;
    float* hp  = ws + OFF_HP;
    float* wp  = ws + OFF_WP;
    float* Mw  = ws + OFF_MW;
    float* Hws = ws + OFF_HWS;
    float* Wws = ws + OFF_WWS;

    // zero the atomic accumulators (hp, wp are contiguous: 6144 floats)
    zero_kernel<<<24, 256, 0, stream>>>(hp, 6144);

    // pools
    pool_kernel<<<B_ * C_, 192, 0, stream>>>(X, cp, hp, wp);

    // Mw[b][r][c] = p[r]*sigmoid(Wc.cp + bc)
    affine_sig_kernel<<<(R_ * C_) / 16, 256, 0, stream>>>(
        Wc, bc, cp, p, Mw, C_, C_, R_ * C_, 1, C_);
    // Hws[b][h][r] = sigmoid(Wh.hp + bh)
    affine_sig_kernel<<<(R_ * H_) / 16, 256, 0, stream>>>(
        Wh, bh, hp, nullptr, Hws, H_, H_, H_ * R_, R_, 1);
    // Wws[b][w][r] = sigmoid(Ww.wp + bw)
    affine_sig_kernel<<<(R_ * W_) / 16, 256, 0, stream>>>(
        Ww, bw, wp, nullptr, Wws, W_, W_, W_ * R_, R_, 1);

    // main fused tile kernel
    main_kernel<<<B_ * 576, 256, 0, stream>>>(X, Mw, Hws, Wws, out);
}

// Round 2
// 403.834 us; speedup vs baseline: 1.1803x; 1.1803x over previous
//
#include <hip/hip_runtime.h>
#include <hip/hip_bf16.h>
#include <math.h>

#define B_  16
#define C_  64
#define H_  192
#define W_  192
#define R_  64
#define HW_ (H_*W_)            // 36864

// ---------------- ws layout (floats) ----------------
// cp   : [B][C]        off 0      size 1024
// hp   : [B][H]        off 1024   size 3072   (atomic accum, needs zero)
// wp   : [B][W]        off 4096   size 3072   (atomic accum, needs zero)
// Mc   : [B][C][R]     off 7168   size 65536  (= p[r]*sigmoid(Wc.cp+bc), c-major!)
// Hws  : [B][H][R]     off 72704  size 196608
// Wws  : [B][W][R]     off 269312 size 196608
#define OFF_CP  0
#define OFF_HP  1024
#define OFF_WP  4096
#define OFF_MC  7168
#define OFF_HWS 72704
#define OFF_WWS 269312

typedef __attribute__((ext_vector_type(8))) short bf16x8;
typedef __attribute__((ext_vector_type(4))) float f32x4;

static __device__ __forceinline__ short f2bf(float f) {
    unsigned u = __float_as_uint(f);
    unsigned r = u + 0x7fffu + ((u >> 16) & 1u);   // RNE
    return (short)(r >> 16);
}

__global__ __launch_bounds__(256) void zero_kernel(float* p, int n) {
    int i = blockIdx.x * 256 + threadIdx.x;
    if (i < n) p[i] = 0.f;
}

// One block per (b,c). 256 threads = 4 waves; wave wv owns rows [48*wv, 48*wv+48).
// Lane owns columns {lane, lane+64, lane+128}. 12 independent loads per unrolled
// chunk of 4 rows -> latency hidden (R0's version stalled on vmcnt(0) per row).
__global__ __launch_bounds__(256) void pool_kernel(const float* __restrict__ X,
                                                   float* __restrict__ cp,
                                                   float* __restrict__ hp,
                                                   float* __restrict__ wp) {
    int b = blockIdx.x >> 6;
    int c = blockIdx.x & 63;
    int tid = threadIdx.x;
    int wv = tid >> 6, lane = tid & 63;
    const float* base = X + (size_t)(b * C_ + c) * HW_ + wv * 48 * W_;

    __shared__ float rowsum[H_];
    __shared__ float colpart[4][W_];
    __shared__ float cpart[3];

    float col0 = 0.f, col1 = 0.f, col2 = 0.f;
    for (int hh = 0; hh < 48; hh += 4) {
        float x[4][3];
        #pragma unroll
        for (int u = 0; u < 4; ++u) {
            #pragma unroll
            for (int k = 0; k < 3; ++k)
                x[u][k] = base[(hh + u) * W_ + k * 64 + lane];
        }
        #pragma unroll
        for (int u = 0; u < 4; ++u) {
            col0 += x[u][0]; col1 += x[u][1]; col2 += x[u][2];
            float s = x[u][0] + x[u][1] + x[u][2];
            s += __shfl_down(s, 32);
            s += __shfl_down(s, 16);
            s += __shfl_down(s, 8);
            s += __shfl_down(s, 4);
            s += __shfl_down(s, 2);
            s += __shfl_down(s, 1);
            if (lane == 0) rowsum[wv * 48 + hh + u] = s;
        }
    }
    colpart[wv][lane]       = col0;
    colpart[wv][lane + 64]  = col1;
    colpart[wv][lane + 128] = col2;
    __syncthreads();

    const float inv_cw = 1.0f / 12288.0f;   // 1/(C*W) == 1/(C*H)
    if (tid < 192) {
        float colv = colpart[0][tid] + colpart[1][tid] + colpart[2][tid] + colpart[3][tid];
        atomicAdd(&wp[b * W_ + tid], colv * inv_cw);
        float rv = rowsum[tid];
        atomicAdd(&hp[b * H_ + tid], rv * inv_cw);
        // cp: reduce rowsum[0..191] (3 full waves)
        float s = rv;
        s += __shfl_down(s, 32);
        s += __shfl_down(s, 16);
        s += __shfl_down(s, 8);
        s += __shfl_down(s, 4);
        s += __shfl_down(s, 2);
        s += __shfl_down(s, 1);
        if ((tid & 63) == 0) cpart[tid >> 6] = s;
    }
    __syncthreads();
    if (tid == 0) cp[b * C_ + c] = (cpart[0] + cpart[1] + cpart[2]) * (1.0f / (float)HW_);
}

// out[...] = (p?p[r]:1) * sigmoid( dot(Wsrc[row,:K], pool[b,:K]) + bias[row] )
__global__ __launch_bounds__(256) void affine_sig_kernel(const float* __restrict__ Wsrc,
                                                         const float* __restrict__ bias,
                                                         const float* __restrict__ pool,
                                                         const float* __restrict__ p,
                                                         float* __restrict__ out,
                                                         int D, int K,
                                                         int s_b, int s_d, int s_r) {
    __shared__ float pl[16 * 193];   // [16][K+1] padded, K<=192
    int tid = threadIdx.x;
    for (int i = tid; i < 16 * K; i += 256) {
        int bb = i / K, kk = i - bb * K;
        pl[bb * (K + 1) + kk] = pool[i];
    }
    __syncthreads();

    int b  = tid & 15;
    int rl = tid >> 4;
    int row = blockIdx.x * 16 + rl;
    int r = row / D, d = row - r * D;

    const float4* w4 = (const float4*)(Wsrc + (size_t)row * K);
    const float*  pb = &pl[b * (K + 1)];
    float acc = 0.f;
    for (int k4 = 0; k4 < (K >> 2); ++k4) {
        float4 wv = w4[k4];
        int k = k4 << 2;
        acc += wv.x * pb[k] + wv.y * pb[k + 1] + wv.z * pb[k + 2] + wv.w * pb[k + 3];
    }
    acc += bias[row];
    float sgm = 1.0f / (1.0f + expf(-acc));
    if (p) sgm *= p[r];
    out[(size_t)b * s_b + (size_t)d * s_d + (size_t)r * s_r] = sgm;
}

// One block per (b, h, 64-wide w strip). 256 threads, 4 waves.
// Per block: 64c x 64j GEMM over r=64, done as bf16 MFMA 16x16x32 with fragments
// built in registers straight from global (no LDS). Wave wv owns c-range [16wv,16wv+16).
// A[m][k] = Mc[b][c0+m][r]   (m=lane&15, k=quad*8+i per m120-verified layout)
// B[k][n] = Hv[r]*Wws[b][w0+jt*16+n][r]
// C/D: col(n)=lane&15, row(m)=quad*4+reg.
__global__ __launch_bounds__(256) void main_kernel(const float* __restrict__ X,
                                                   const float* __restrict__ Mc,
                                                   const float* __restrict__ Hws,
                                                   const float* __restrict__ Wws,
                                                   float* __restrict__ out) {
    int blk = blockIdx.x;
    int b = blk / 576;
    int rem = blk - b * 576;
    int h = rem / 3;
    int w0 = (rem - h * 3) * 64;
    int tid = threadIdx.x;
    int wv = tid >> 6, lane = tid & 63;
    int m = lane & 15, quad = lane >> 4;
    int c0 = wv * 16;

    const float* McB = Mc + b * (C_ * R_);
    const float* HvB = Hws + ((size_t)b * H_ + h) * R_;
    const float* WwB = Wws + ((size_t)b * W_ + w0) * R_;

    bf16x8 afrag[2];
    float hv[2][8];
    #pragma unroll
    for (int ks = 0; ks < 2; ++ks) {
        const float4* ap = (const float4*)(McB + (c0 + m) * R_ + ks * 32 + quad * 8);
        const float4* hpp = (const float4*)(HvB + ks * 32 + quad * 8);
        float4 a0 = ap[0], a1 = ap[1];
        float4 h0 = hpp[0], h1 = hpp[1];
        afrag[ks][0] = f2bf(a0.x); afrag[ks][1] = f2bf(a0.y);
        afrag[ks][2] = f2bf(a0.z); afrag[ks][3] = f2bf(a0.w);
        afrag[ks][4] = f2bf(a1.x); afrag[ks][5] = f2bf(a1.y);
        afrag[ks][6] = f2bf(a1.z); afrag[ks][7] = f2bf(a1.w);
        hv[ks][0] = h0.x; hv[ks][1] = h0.y; hv[ks][2] = h0.z; hv[ks][3] = h0.w;
        hv[ks][4] = h1.x; hv[ks][5] = h1.y; hv[ks][6] = h1.z; hv[ks][7] = h1.w;
    }

    f32x4 acc[4];
    #pragma unroll
    for (int jt = 0; jt < 4; ++jt) acc[jt] = (f32x4){0.f, 0.f, 0.f, 0.f};

    #pragma unroll
    for (int jt = 0; jt < 4; ++jt) {
        #pragma unroll
        for (int ks = 0; ks < 2; ++ks) {
            const float4* bp = (const float4*)(WwB + (jt * 16 + m) * R_ + ks * 32 + quad * 8);
            float4 b0 = bp[0], b1 = bp[1];
            bf16x8 bfrag;
            bfrag[0] = f2bf(b0.x * hv[ks][0]); bfrag[1] = f2bf(b0.y * hv[ks][1]);
            bfrag[2] = f2bf(b0.z * hv[ks][2]); bfrag[3] = f2bf(b0.w * hv[ks][3]);
            bfrag[4] = f2bf(b1.x * hv[ks][4]); bfrag[5] = f2bf(b1.y * hv[ks][5]);
            bfrag[6] = f2bf(b1.z * hv[ks][6]); bfrag[7] = f2bf(b1.w * hv[ks][7]);
            acc[jt] = __builtin_amdgcn_mfma_f32_16x16x32_bf16(afrag[ks], bfrag, acc[jt], 0, 0, 0);
        }
    }

    // epilogue: out[b, c, h, w0 + jt*16 + m] = acc * X
    size_t pixbase = (size_t)h * W_ + w0 + m;
    #pragma unroll
    for (int jt = 0; jt < 4; ++jt) {
        #pragma unroll
        for (int reg = 0; reg < 4; ++reg) {
            int c = c0 + quad * 4 + reg;
            size_t idx = (size_t)(b * C_ + c) * HW_ + pixbase + jt * 16;
            out[idx] = acc[jt][reg] * X[idx];
        }
    }
}

extern "C" void kernel_launch(void* const* d_in, const int* in_sizes, int n_in,
                              void* d_out, int out_size, void* d_ws, size_t ws_size,
                              hipStream_t stream) {
    const float* X  = (const float*)d_in[0];
    const float* p  = (const float*)d_in[1];
    const float* Wc = (const float*)d_in[2];
    const float* bc = (const float*)d_in[3];
    const float* Wh = (const float*)d_in[4];
    const float* bh = (const float*)d_in[5];
    const float* Ww = (const float*)d_in[6];
    const float* bw = (const float*)d_in[7];
    float* out = (float*)d_out;
    float* ws  = (float*)d_ws;

    float* cp  = ws + OFF_CP;
    float* hp  = ws + OFF_HP;
    float* wp  = ws + OFF_WP;
    float* Mc  = ws + OFF_MC;
    float* Hws = ws + OFF_HWS;
    float* Wws = ws + OFF_WWS;

    // zero the atomic accumulators (hp, wp contiguous: 6144 floats)
    zero_kernel<<<24, 256, 0, stream>>>(hp, 6144);

    pool_kernel<<<B_ * C_, 256, 0, stream>>>(X, cp, hp, wp);

    // Mc[b][c][r] = p[r]*sigmoid(Wc.cp + bc)   (c-major for MFMA A-frag reads)
    affine_sig_kernel<<<(R_ * C_) / 16, 256, 0, stream>>>(
        Wc, bc, cp, p, Mc, C_, C_, C_ * R_, R_, 1);
    // Hws[b][h][r] = sigmoid(Wh.hp + bh)
    affine_sig_kernel<<<(R_ * H_) / 16, 256, 0, stream>>>(
        Wh, bh, hp, nullptr, Hws, H_, H_, H_ * R_, R_, 1);
    // Wws[b][w][r] = sigmoid(Ww.wp + bw)
    affine_sig_kernel<<<(R_ * W_) / 16, 256, 0, stream>>>(
        Ww, bw, wp, nullptr, Wws, W_, W_, W_ * R_, R_, 1);

    main_kernel<<<B_ * 576, 256, 0, stream>>>(X, Mc, Hws, Wws, out);
}

// Round 3
// 395.180 us; speedup vs baseline: 1.2061x; 1.0219x over previous
//
#include <hip/hip_runtime.h>
#include <hip/hip_bf16.h>
#include <math.h>

#define B_  16
#define C_  64
#define H_  192
#define W_  192
#define R_  64
#define HW_ (H_*W_)            // 36864

// ---------------- ws layout (floats) ----------------
#define OFF_CP  0
#define OFF_HP  1024
#define OFF_WP  4096
#define OFF_MC  7168
#define OFF_HWS 72704
#define OFF_WWS 269312

typedef __attribute__((ext_vector_type(8))) short bf16x8;
typedef __attribute__((ext_vector_type(4))) float f32x4;

static __device__ __forceinline__ short f2bf(float f) {
    unsigned u = __float_as_uint(f);
    unsigned r = u + 0x7fffu + ((u >> 16) & 1u);   // RNE
    return (short)(r >> 16);
}

__global__ __launch_bounds__(256) void zero_kernel(float* p, int n) {
    int i = blockIdx.x * 256 + threadIdx.x;
    if (i < n) p[i] = 0.f;
}

// One block per (b,c). 256 threads = 4 waves; wave wv owns rows [48*wv, 48*wv+48).
// Lane owns columns {lane, lane+64, lane+128}. 12 independent loads per unrolled
// chunk of 4 rows -> latency hidden.
__global__ __launch_bounds__(256) void pool_kernel(const float* __restrict__ X,
                                                   float* __restrict__ cp,
                                                   float* __restrict__ hp,
                                                   float* __restrict__ wp) {
    int b = blockIdx.x >> 6;
    int c = blockIdx.x & 63;
    int tid = threadIdx.x;
    int wv = tid >> 6, lane = tid & 63;
    const float* base = X + (size_t)(b * C_ + c) * HW_ + wv * 48 * W_;

    __shared__ float rowsum[H_];
    __shared__ float colpart[4][W_];
    __shared__ float cpart[3];

    float col0 = 0.f, col1 = 0.f, col2 = 0.f;
    for (int hh = 0; hh < 48; hh += 4) {
        float x[4][3];
        #pragma unroll
        for (int u = 0; u < 4; ++u) {
            #pragma unroll
            for (int k = 0; k < 3; ++k)
                x[u][k] = base[(hh + u) * W_ + k * 64 + lane];
        }
        #pragma unroll
        for (int u = 0; u < 4; ++u) {
            col0 += x[u][0]; col1 += x[u][1]; col2 += x[u][2];
            float s = x[u][0] + x[u][1] + x[u][2];
            s += __shfl_down(s, 32);
            s += __shfl_down(s, 16);
            s += __shfl_down(s, 8);
            s += __shfl_down(s, 4);
            s += __shfl_down(s, 2);
            s += __shfl_down(s, 1);
            if (lane == 0) rowsum[wv * 48 + hh + u] = s;
        }
    }
    colpart[wv][lane]       = col0;
    colpart[wv][lane + 64]  = col1;
    colpart[wv][lane + 128] = col2;
    __syncthreads();

    const float inv_cw = 1.0f / 12288.0f;   // 1/(C*W) == 1/(C*H)
    if (tid < 192) {
        float colv = colpart[0][tid] + colpart[1][tid] + colpart[2][tid] + colpart[3][tid];
        atomicAdd(&wp[b * W_ + tid], colv * inv_cw);
        float rv = rowsum[tid];
        atomicAdd(&hp[b * H_ + tid], rv * inv_cw);
        float s = rv;
        s += __shfl_down(s, 32);
        s += __shfl_down(s, 16);
        s += __shfl_down(s, 8);
        s += __shfl_down(s, 4);
        s += __shfl_down(s, 2);
        s += __shfl_down(s, 1);
        if ((tid & 63) == 0) cpart[tid >> 6] = s;
    }
    __syncthreads();
    if (tid == 0) cp[b * C_ + c] = (cpart[0] + cpart[1] + cpart[2]) * (1.0f / (float)HW_);
}

// All three affine+sigmoid maps in ONE launch, partitioned by blockIdx:
//   [0,256)      : Mc [b][c][r] = p[r]*sigmoid(Wc.cp+bc)      D=K=64
//   [256,1024)   : Hws[b][h][r] = sigmoid(Wh.hp+bh)           D=K=192
//   [1024,1792)  : Wws[b][w][r] = sigmoid(Ww.wp+bw)           D=K=192
__global__ __launch_bounds__(256) void affine_all_kernel(
        const float* __restrict__ Wc, const float* __restrict__ bc,
        const float* __restrict__ Wh, const float* __restrict__ bh,
        const float* __restrict__ Ww, const float* __restrict__ bw,
        const float* __restrict__ cp, const float* __restrict__ hp,
        const float* __restrict__ wp, const float* __restrict__ p,
        float* __restrict__ Mc, float* __restrict__ Hws, float* __restrict__ Wws) {
    __shared__ float pl[16 * 193];
    int blk = blockIdx.x;
    const float *Wsrc, *bias, *pool, *pmul;
    float* outp;
    int D, K;
    if (blk < 256) {
        Wsrc = Wc; bias = bc; pool = cp; pmul = p; outp = Mc; D = C_; K = C_;
    } else if (blk < 1024) {
        blk -= 256;
        Wsrc = Wh; bias = bh; pool = hp; pmul = nullptr; outp = Hws; D = H_; K = H_;
    } else {
        blk -= 1024;
        Wsrc = Ww; bias = bw; pool = wp; pmul = nullptr; outp = Wws; D = W_; K = W_;
    }

    int tid = threadIdx.x;
    for (int i = tid; i < 16 * K; i += 256) {
        int bb = i / K, kk = i - bb * K;
        pl[bb * (K + 1) + kk] = pool[i];
    }
    __syncthreads();

    int b  = tid & 15;
    int rl = tid >> 4;
    int row = blk * 16 + rl;
    int r = row / D, d = row - r * D;

    const float4* w4 = (const float4*)(Wsrc + (size_t)row * K);
    const float*  pb = &pl[b * (K + 1)];
    float acc = 0.f;
    for (int k4 = 0; k4 < (K >> 2); ++k4) {
        float4 wv = w4[k4];
        int k = k4 << 2;
        acc += wv.x * pb[k] + wv.y * pb[k + 1] + wv.z * pb[k + 2] + wv.w * pb[k + 3];
    }
    acc += bias[row];
    float sgm = 1.0f / (1.0f + expf(-acc));
    if (pmul) sgm *= pmul[r];
    // Mc: [b][c][r] (strides: b->C*R, d(c)->R, r->1); H/W: [b][x][r]
    if (D == C_)
        outp[(size_t)b * (C_ * R_) + (size_t)d * R_ + r] = sgm;
    else
        outp[(size_t)b * (D * R_) + (size_t)d * R_ + r] = sgm;
}

// One block per (b, h, 64-wide w strip). 256 threads, 4 waves.
// TRANSPOSED vs R2: A[m][k] = Hv[r]*Wws[b][w][r]  (m = w within wave's 16-w tile),
//                   B[k][n] = Mc[b][c][r]          (n = c within ct*16 tile).
// D: col(n=lane&15) = c, row(quad*4+reg) = w  ->  reg spans 4 CONTIGUOUS w's
// -> float4 X-load / float4 store epilogue (R2 used 16 scalar dwords each way).
__global__ __launch_bounds__(256) void main_kernel(const float* __restrict__ X,
                                                   const float* __restrict__ Mc,
                                                   const float* __restrict__ Hws,
                                                   const float* __restrict__ Wws,
                                                   float* __restrict__ out) {
    int blk = blockIdx.x;
    int b = blk / 576;
    int rem = blk - b * 576;
    int h = rem / 3;
    int w0 = (rem - h * 3) * 64;
    int tid = threadIdx.x;
    int wv = tid >> 6, lane = tid & 63;
    int m = lane & 15, quad = lane >> 4;

    const float* McB = Mc + b * (C_ * R_);
    const float* HvB = Hws + ((size_t)b * H_ + h) * R_;
    const float* WwB = Wws + ((size_t)b * W_ + w0) * R_;

    // X prefetch: lane covers c = ct*16+m, w = w0 + wv*16 + quad*4 .. +3
    int wbase = w0 + wv * 16 + quad * 4;
    size_t pixbase = (size_t)h * W_ + wbase;
    float4 xv[4];
    #pragma unroll
    for (int ct = 0; ct < 4; ++ct) {
        int c = ct * 16 + m;
        xv[ct] = *(const float4*)(X + (size_t)(b * C_ + c) * HW_ + pixbase);
    }

    // A frag: rows = 16 w's of this wave; per-lane row m, k = quad*8+i
    bf16x8 afrag[2];
    #pragma unroll
    for (int ks = 0; ks < 2; ++ks) {
        const float4* wp4 = (const float4*)(WwB + (wv * 16 + m) * R_ + ks * 32 + quad * 8);
        const float4* hp4 = (const float4*)(HvB + ks * 32 + quad * 8);
        float4 w0v = wp4[0], w1v = wp4[1];
        float4 h0v = hp4[0], h1v = hp4[1];
        afrag[ks][0] = f2bf(w0v.x * h0v.x); afrag[ks][1] = f2bf(w0v.y * h0v.y);
        afrag[ks][2] = f2bf(w0v.z * h0v.z); afrag[ks][3] = f2bf(w0v.w * h0v.w);
        afrag[ks][4] = f2bf(w1v.x * h1v.x); afrag[ks][5] = f2bf(w1v.y * h1v.y);
        afrag[ks][6] = f2bf(w1v.z * h1v.z); afrag[ks][7] = f2bf(w1v.w * h1v.w);
    }

    f32x4 acc[4];
    #pragma unroll
    for (int ct = 0; ct < 4; ++ct) acc[ct] = (f32x4){0.f, 0.f, 0.f, 0.f};

    #pragma unroll
    for (int ct = 0; ct < 4; ++ct) {
        #pragma unroll
        for (int ks = 0; ks < 2; ++ks) {
            // B frag: B[k][n] with n = c = ct*16 + m (per-lane), k = quad*8+i
            const float4* bp = (const float4*)(McB + (ct * 16 + m) * R_ + ks * 32 + quad * 8);
            float4 b0 = bp[0], b1 = bp[1];
            bf16x8 bfrag;
            bfrag[0] = f2bf(b0.x); bfrag[1] = f2bf(b0.y);
            bfrag[2] = f2bf(b0.z); bfrag[3] = f2bf(b0.w);
            bfrag[4] = f2bf(b1.x); bfrag[5] = f2bf(b1.y);
            bfrag[6] = f2bf(b1.z); bfrag[7] = f2bf(b1.w);
            acc[ct] = __builtin_amdgcn_mfma_f32_16x16x32_bf16(afrag[ks], bfrag, acc[ct], 0, 0, 0);
        }
    }

    // epilogue: float4 per (thread, ct)
    #pragma unroll
    for (int ct = 0; ct < 4; ++ct) {
        int c = ct * 16 + m;
        float4 o;
        o.x = acc[ct][0] * xv[ct].x;
        o.y = acc[ct][1] * xv[ct].y;
        o.z = acc[ct][2] * xv[ct].z;
        o.w = acc[ct][3] * xv[ct].w;
        *(float4*)(out + (size_t)(b * C_ + c) * HW_ + pixbase) = o;
    }
}

extern "C" void kernel_launch(void* const* d_in, const int* in_sizes, int n_in,
                              void* d_out, int out_size, void* d_ws, size_t ws_size,
                              hipStream_t stream) {
    const float* X  = (const float*)d_in[0];
    const float* p  = (const float*)d_in[1];
    const float* Wc = (const float*)d_in[2];
    const float* bc = (const float*)d_in[3];
    const float* Wh = (const float*)d_in[4];
    const float* bh = (const float*)d_in[5];
    const float* Ww = (const float*)d_in[6];
    const float* bw = (const float*)d_in[7];
    float* out = (float*)d_out;
    float* ws  = (float*)d_ws;

    float* cp  = ws + OFF_CP;
    float* hp  = ws + OFF_HP;
    float* wp  = ws + OFF_WP;
    float* Mc  = ws + OFF_MC;
    float* Hws = ws + OFF_HWS;
    float* Wws = ws + OFF_WWS;

    zero_kernel<<<24, 256, 0, stream>>>(hp, 6144);

    pool_kernel<<<B_ * C_, 256, 0, stream>>>(X, cp, hp, wp);

    affine_all_kernel<<<1792, 256, 0, stream>>>(Wc, bc, Wh, bh, Ww, bw,
                                                cp, hp, wp, p, Mc, Hws, Wws);

    main_kernel<<<B_ * 576, 256, 0, stream>>>(X, Mc, Hws, Wws, out);
}